// Round 1
// baseline (808.817 us; speedup 1.0000x reference)
//
#include <hip/hip_runtime.h>
#include <stdint.h>

#define NN 5000
#define NE 80000
#define NF 128
#define NT 16
#define TN 10
#define NFW 3
#define NSK 10
#define TPB 512
#define RPT 10   // ceil(NN / TPB)

// ---------- workspace layout (bytes) ----------
#define OFF_DEG   0u
#define OFF_RP    20224u
#define OFF_CUR   40448u
#define OFF_COL   60672u
#define OFF_M     380672u
#define OFF_T     4220672u
#define OFF_DT    8060672u
#define OFF_ATC   11900672u
#define SMEM_BYTES (160000 + 224)

// ---------- helpers ----------
__device__ __forceinline__ uint32_t bfb(float x) {
  uint32_t u = __float_as_uint(x);
  return (u + 0x7fffu + ((u >> 16) & 1u)) >> 16;
}
__device__ __forceinline__ uint32_t pk(float a, float b) { return bfb(a) | (bfb(b) << 16); }
__device__ __forceinline__ float ubl(uint32_t u) { return __uint_as_float(u << 16); }
__device__ __forceinline__ float ubh(uint32_t u) { return __uint_as_float(u & 0xffff0000u); }

__device__ __forceinline__ void ld12(const float* p, float* v) {
  float4 a = ((const float4*)p)[0], b = ((const float4*)p)[1], c = ((const float4*)p)[2];
  v[0]=a.x; v[1]=a.y; v[2]=a.z; v[3]=a.w; v[4]=b.x; v[5]=b.y; v[6]=b.z; v[7]=b.w; v[8]=c.x; v[9]=c.y;
}
__device__ __forceinline__ void st12(float* p, const float* v) {
  ((float4*)p)[0] = make_float4(v[0], v[1], v[2], v[3]);
  ((float4*)p)[1] = make_float4(v[4], v[5], v[6], v[7]);
  ((float4*)p)[2] = make_float4(v[8], v[9], 0.f, 0.f);
}

__device__ __forceinline__ float bsum(float v, float* red) {
  const int lane = threadIdx.x & 63, wid = threadIdx.x >> 6;
  #pragma unroll
  for (int o = 32; o; o >>= 1) v += __shfl_xor(v, o, 64);
  __syncthreads();                       // protect red from previous use
  if (lane == 0) red[wid] = v;
  __syncthreads();
  float r = red[0];
  #pragma unroll
  for (int w = 1; w < TPB / 64; ++w) r += red[w];
  return r;
}
__device__ __forceinline__ float bmin(float v, float* red) {
  const int lane = threadIdx.x & 63, wid = threadIdx.x >> 6;
  #pragma unroll
  for (int o = 32; o; o >>= 1) v = fminf(v, __shfl_xor(v, o, 64));
  __syncthreads();
  if (lane == 0) red[wid] = v;
  __syncthreads();
  float r = red[0];
  #pragma unroll
  for (int w = 1; w < TPB / 64; ++w) r = fminf(r, red[w]);
  return r;
}

__device__ __forceinline__ void gather_row(const uint32_t* Yb, const int* __restrict__ colidx,
                                           int e0, int e1, float* acc) {
  for (int e = e0; e < e1; ++e) {
    int c = colidx[e];
    const uint32_t* r = Yb + c * 8;
    uint4 A = *(const uint4*)r;
    uint2 B = *(const uint2*)(r + 4);
    acc[0] += ubl(A.x); acc[1] += ubh(A.x); acc[2] += ubl(A.y); acc[3] += ubh(A.y);
    acc[4] += ubl(A.z); acc[5] += ubh(A.z); acc[6] += ubl(A.w); acc[7] += ubh(A.w);
    acc[8] += ubl(B.x); acc[9] += ubh(B.x);
  }
}

__device__ __forceinline__ void ybuild_store(uint32_t* Yb, int i, const float* Trow,
                                             const float* __restrict__ C2k) {
  float y[TN];
  #pragma unroll
  for (int j = 0; j < TN; ++j) {
    float s = 0.f;
    #pragma unroll
    for (int l = 0; l < TN; ++l) s += Trow[l] * C2k[l * TN + j];  // C2k uniform -> s_load
    y[j] = s;
  }
  *(uint4*)(Yb + i * 8)     = make_uint4(pk(y[0], y[1]), pk(y[2], y[3]), pk(y[4], y[5]), pk(y[6], y[7]));
  *(uint4*)(Yb + i * 8 + 4) = make_uint4(pk(y[8], y[9]), 0u, 0u, 0u);
}

// ---------- setup kernels ----------
__global__ void k_zero(int* __restrict__ deg) {
  int i = blockIdx.x * 256 + threadIdx.x;
  if (i < NN) deg[i] = 0;
}
__global__ void k_deg(const int* __restrict__ ei, int* __restrict__ deg) {
  int e = blockIdx.x * 256 + threadIdx.x;
  if (e < NE) atomicAdd(&deg[ei[e]], 1);
}
__global__ void k_scan(const int* __restrict__ deg, int* __restrict__ rowptr, int* __restrict__ cur) {
  __shared__ int scr[1024];
  int tid = threadIdx.x;
  int loc[5], s = 0;
  #pragma unroll
  for (int r = 0; r < 5; ++r) {
    int idx = tid * 5 + r;
    int d = (idx < NN) ? deg[idx] : 0;
    loc[r] = s; s += d;
  }
  scr[tid] = s; __syncthreads();
  for (int off = 1; off < 1024; off <<= 1) {
    int v = scr[tid];
    int u = (tid >= off) ? scr[tid - off] : 0;
    __syncthreads();
    scr[tid] = v + u;
    __syncthreads();
  }
  int base = (tid > 0) ? scr[tid - 1] : 0;
  #pragma unroll
  for (int r = 0; r < 5; ++r) {
    int idx = tid * 5 + r;
    if (idx < NN) { int v = base + loc[r]; rowptr[idx] = v; cur[idx] = v; }
  }
  if (tid == 1023) rowptr[NN] = scr[1023];
}
__global__ void k_fill(const int* __restrict__ ei, int* __restrict__ cur, int* __restrict__ col) {
  int e = blockIdx.x * 256 + threadIdx.x;
  if (e < NE) {
    int s = ei[e];
    int pos = atomicAdd(&cur[s], 1);
    col[pos] = ei[NE + e];
  }
}
// M[k][i][j] = ||x_i||^2 + ||f_kj||^2 - 2 x_i . f_kj   (rows padded to 12)
__global__ void k_mbuild(const float* __restrict__ x, const float* __restrict__ F2,
                         float* __restrict__ M) {
  __shared__ float ffs[TN];
  const int k = blockIdx.y;
  const int i = blockIdx.x * 128 + threadIdx.x;
  const float* F = F2 + (size_t)k * TN * NF;
  if (threadIdx.x < TN) {
    float s = 0.f;
    for (int d = 0; d < NF; ++d) { float f = F[threadIdx.x * NF + d]; s += f * f; }
    ffs[threadIdx.x] = s;
  }
  __syncthreads();
  if (i >= NN) return;
  const float4* xr = (const float4*)(x + (size_t)i * NF);
  float acc[TN];
  #pragma unroll
  for (int j = 0; j < TN; ++j) acc[j] = 0.f;
  float xsq = 0.f;
  for (int dc = 0; dc < NF / 4; ++dc) {
    float4 xv = xr[dc];
    xsq += xv.x * xv.x + xv.y * xv.y + xv.z * xv.z + xv.w * xv.w;
    #pragma unroll
    for (int j = 0; j < TN; ++j) {
      const float* Fj = F + j * NF + dc * 4;  // uniform -> scalar loads
      acc[j] += xv.x * Fj[0] + xv.y * Fj[1] + xv.z * Fj[2] + xv.w * Fj[3];
    }
  }
  float* Mr = M + ((size_t)k * NN + i) * 12;
  float v[TN];
  #pragma unroll
  for (int j = 0; j < TN; ++j) v[j] = xsq + ffs[j] - 2.f * acc[j];
  st12(Mr, v);
}

// ---------- main kernel: one block per template ----------
__global__ __launch_bounds__(TPB, 2) void fgw_main(
    const float* __restrict__ M, const int* __restrict__ rowptr, const int* __restrict__ colidx,
    const float* __restrict__ C2g, const float* __restrict__ q0, const float* __restrict__ alpha0,
    float* __restrict__ Tg, float* __restrict__ dTg, float* __restrict__ ATCg,
    float* __restrict__ out) {
  extern __shared__ char smem[];
  uint32_t* Yb = (uint32_t*)smem;              // [NN][8] u32 = 16 bf16/row
  float* fp = (float*)(smem + 160000);
  float* qv = fp;        // 10
  float* wv = fp + 10;   // 10
  float* wp = fp + 20;   // 10
  float* cs = fp + 30;   // 10
  float* red = fp + 40;  // 16

  const int k = blockIdx.x, tid = threadIdx.x;
  const float p = 1.0f / NN;
  const float* C2k = C2g + (size_t)k * 100;
  const float* Mk = M + (size_t)k * NN * 12;
  float* Tk  = Tg  + (size_t)k * NN * 12;
  float* dTk = dTg + (size_t)k * NN * 12;
  float* Ak  = ATCg + (size_t)k * NN * 12;

  if (tid == 0) {  // softmax of q0 row
    float mx = -1e30f;
    for (int j = 0; j < TN; ++j) mx = fmaxf(mx, q0[k * TN + j]);
    float e[TN], s = 0.f;
    for (int j = 0; j < TN; ++j) { e[j] = __expf(q0[k * TN + j] - mx); s += e[j]; }
    for (int j = 0; j < TN; ++j) qv[j] = e[j] / s;
    for (int j = 0; j < TN; ++j) cs[j] = 0.f;
  }
  __syncthreads();
  const float alpha = 1.f / (1.f + __expf(-alpha0[0]));
  const float oma = 1.f - alpha;
  float c2q[TN];
  #pragma unroll
  for (int j = 0; j < TN; ++j) {
    float s = 0.f;
    #pragma unroll
    for (int l = 0; l < TN; ++l) { float c = C2k[j * TN + l]; s += c * c * qv[l]; }
    c2q[j] = s;
  }

  float regb[RPT][TN];   // G -> E -> dT (t<3), Trow stash (t==3)
  float ccr[RPT];
  float gamma = 0.f;

  for (int t = 0; t <= NFW; ++t) {
    // ---- P1: T update + Y(bf16) build into LDS ----
    #pragma unroll
    for (int m = 0; m < RPT; ++m) {
      int i = tid + m * TPB;
      if (i < NN) {
        float Trow[TN];
        if (t == 0) {
          #pragma unroll
          for (int j = 0; j < TN; ++j) Trow[j] = p * qv[j];
        } else {
          float tv[TN], dv[TN];
          ld12(Tk + i * 12, tv); ld12(dTk + i * 12, dv);
          #pragma unroll
          for (int j = 0; j < TN; ++j) Trow[j] = tv[j] + gamma * dv[j];
        }
        if (t < NFW) st12(Tk + i * 12, Trow);
        else {
          #pragma unroll
          for (int j = 0; j < TN; ++j) regb[m][j] = Trow[j];
        }
        ybuild_store(Yb, i, Trow, C2k);
      }
    }
    __syncthreads();

    if (t < NFW) {
      // ---- P2: gather ATC, G into regs, |G| and min stats ----
      float sabs = 0.f, mn = 1e30f;
      #pragma unroll
      for (int m = 0; m < RPT; ++m) {
        int i = tid + m * TPB;
        ccr[m] = 0.f;
        if (i < NN) {
          int e0 = rowptr[i], e1 = rowptr[i + 1];
          float atc[TN];
          #pragma unroll
          for (int j = 0; j < TN; ++j) atc[j] = 0.f;
          gather_row(Yb, colidx, e0, e1, atc);
          st12(Ak + i * 12, atc);
          float cc = (float)(e1 - e0) * p;
          ccr[m] = cc;
          float mv[TN]; ld12(Mk + i * 12, mv);
          #pragma unroll
          for (int j = 0; j < TN; ++j) {
            float G = oma * mv[j] + 2.f * alpha * (cc + c2q[j] - 2.f * atc[j]);
            regb[m][j] = G;
            sabs += fabsf(G);
            mn = fminf(mn, G);
          }
        }
      }
      sabs = bsum(sabs, red);
      mn = bmin(mn, red);
      const float reg = 0.05f * sabs / (float)(NN * TN) + 1e-9f;
      const float invreg = 1.f / reg;

      // ---- P3: E = exp(-(G-mn)/reg) in registers ----
      #pragma unroll
      for (int m = 0; m < RPT; ++m) {
        int i = tid + m * TPB;
        if (i < NN) {
          #pragma unroll
          for (int j = 0; j < TN; ++j) regb[m][j] = __expf(-(regb[m][j] - mn) * invreg);
        }
      }

      // ---- P4: Sinkhorn (normal domain), 10 iters ----
      if (tid < TN) { wv[tid] = 1.f; cs[tid] = 0.f; }
      __syncthreads();
      for (int it = 0; it < NSK; ++it) {
        float wr[TN];
        #pragma unroll
        for (int j = 0; j < TN; ++j) wr[j] = wv[j];
        float csl[TN];
        #pragma unroll
        for (int j = 0; j < TN; ++j) csl[j] = 0.f;
        #pragma unroll
        for (int m = 0; m < RPT; ++m) {
          int i = tid + m * TPB;
          if (i < NN) {
            float dot = 0.f;
            #pragma unroll
            for (int j = 0; j < TN; ++j) dot += regb[m][j] * wr[j];
            float u = p / fmaxf(dot, 1e-35f);
            #pragma unroll
            for (int j = 0; j < TN; ++j) csl[j] += regb[m][j] * u;
          }
        }
        #pragma unroll
        for (int j = 0; j < TN; ++j) {
          float v = csl[j];
          #pragma unroll
          for (int o = 32; o; o >>= 1) v += __shfl_xor(v, o, 64);
          if ((tid & 63) == 0) atomicAdd(&cs[j], v);
        }
        __syncthreads();
        if (tid < TN) {
          wp[tid] = wv[tid];
          wv[tid] = qv[tid] / fmaxf(cs[tid], 1e-35f);
          cs[tid] = 0.f;
        }
        __syncthreads();
      }

      // ---- P5: dT = T_new - T (into regs + global), b-dots ----
      float wr[TN], wl[TN];
      #pragma unroll
      for (int j = 0; j < TN; ++j) { wr[j] = wp[j]; wl[j] = wv[j]; }
      float bM = 0.f, bC = 0.f, bA = 0.f;
      #pragma unroll
      for (int m = 0; m < RPT; ++m) {
        int i = tid + m * TPB;
        if (i < NN) {
          float dot = 0.f;
          #pragma unroll
          for (int j = 0; j < TN; ++j) dot += regb[m][j] * wr[j];
          float u = p / fmaxf(dot, 1e-35f);
          float tv[TN], mv[TN], av[TN];
          ld12(Tk + i * 12, tv); ld12(Mk + i * 12, mv); ld12(Ak + i * 12, av);
          float dv[TN];
          #pragma unroll
          for (int j = 0; j < TN; ++j) {
            float Tn = u * regb[m][j] * wl[j];
            float d = Tn - tv[j];
            regb[m][j] = d; dv[j] = d;
            bM += mv[j] * d;
            bC += (ccr[m] + c2q[j]) * d;
            bA += av[j] * d;
          }
          st12(dTk + i * 12, dv);
        }
      }
      bM = bsum(bM, red); bC = bsum(bC, red); bA = bsum(bA, red);

      // ---- P6: Y2 = dT @ C2 into LDS ----
      #pragma unroll
      for (int m = 0; m < RPT; ++m) {
        int i = tid + m * TPB;
        if (i < NN) ybuild_store(Yb, i, regb[m], C2k);
      }
      __syncthreads();

      // ---- P7: AdTC gather + a-dot, line search ----
      float aacc = 0.f;
      #pragma unroll
      for (int m = 0; m < RPT; ++m) {
        int i = tid + m * TPB;
        if (i < NN) {
          int e0 = rowptr[i], e1 = rowptr[i + 1];
          float ad[TN];
          #pragma unroll
          for (int j = 0; j < TN; ++j) ad[j] = 0.f;
          gather_row(Yb, colidx, e0, e1, ad);
          #pragma unroll
          for (int j = 0; j < TN; ++j) aacc += ad[j] * regb[m][j];
        }
      }
      aacc = bsum(aacc, red);
      float a_ = -2.f * alpha * aacc;
      float b_ = oma * bM + alpha * (bC - 4.f * bA);
      if (a_ > 0.f) gamma = fminf(fmaxf(-b_ / (2.f * a_ + 1e-16f), 0.f), 1.f);
      else gamma = (a_ + b_ < 0.f) ? 1.f : 0.f;
    } else {
      // ---- final distance ----
      float d1 = 0.f, d2 = 0.f, d3 = 0.f;
      #pragma unroll
      for (int m = 0; m < RPT; ++m) {
        int i = tid + m * TPB;
        if (i < NN) {
          int e0 = rowptr[i], e1 = rowptr[i + 1];
          float cc = (float)(e1 - e0) * p;
          float atc[TN];
          #pragma unroll
          for (int j = 0; j < TN; ++j) atc[j] = 0.f;
          gather_row(Yb, colidx, e0, e1, atc);
          float mv[TN]; ld12(Mk + i * 12, mv);
          #pragma unroll
          for (int j = 0; j < TN; ++j) {
            float Tv = regb[m][j];
            d1 += mv[j] * Tv;
            d2 += (cc + c2q[j]) * Tv;
            d3 += atc[j] * Tv;
          }
        }
      }
      d1 = bsum(d1, red); d2 = bsum(d2, red); d3 = bsum(d3, red);
      if (tid == 0) out[k] = oma * d1 + alpha * (d2 - 2.f * d3);
    }
  }
}

extern "C" void kernel_launch(void* const* d_in, const int* in_sizes, int n_in,
                              void* d_out, int out_size, void* d_ws, size_t ws_size,
                              hipStream_t stream) {
  const float* x  = (const float*)d_in[0];
  const int*   ei = (const int*)d_in[1];
  const float* C2 = (const float*)d_in[2];
  const float* F2 = (const float*)d_in[3];
  const float* q0 = (const float*)d_in[4];
  const float* a0 = (const float*)d_in[5];
  float* out = (float*)d_out;

  char* ws = (char*)d_ws;
  int* deg    = (int*)(ws + OFF_DEG);
  int* rowptr = (int*)(ws + OFF_RP);
  int* cur    = (int*)(ws + OFF_CUR);
  int* col    = (int*)(ws + OFF_COL);
  float* M    = (float*)(ws + OFF_M);
  float* T    = (float*)(ws + OFF_T);
  float* dT   = (float*)(ws + OFF_DT);
  float* ATC  = (float*)(ws + OFF_ATC);

  hipFuncSetAttribute((const void*)fgw_main, hipFuncAttributeMaxDynamicSharedMemorySize, SMEM_BYTES);

  k_zero<<<(NN + 255) / 256, 256, 0, stream>>>(deg);
  k_deg<<<(NE + 255) / 256, 256, 0, stream>>>(ei, deg);
  k_scan<<<1, 1024, 0, stream>>>(deg, rowptr, cur);
  k_fill<<<(NE + 255) / 256, 256, 0, stream>>>(ei, cur, col);
  k_mbuild<<<dim3((NN + 127) / 128, NT), 128, 0, stream>>>(x, F2, M);
  fgw_main<<<NT, TPB, SMEM_BYTES, stream>>>(M, rowptr, col, C2, q0, a0, T, dT, ATC, out);
}